// Round 2
// baseline (4558.401 us; speedup 1.0000x reference)
//
#include <hip/hip_runtime.h>

// MultiHeadAttentionConvIndex — fp32, spill-free edge kernel.
// Softmax max-shift dropped (shift-invariant; logits are O(0.1) here).
// ws layout (floats): agg[N*96] | denom[N*4] | count[N]

#define NEG 0.01f

__device__ __forceinline__ float lrelu(float v) { return v > 0.f ? v : NEG * v; }

__global__ void zero_kernel(float* __restrict__ p, long n) {
    long i = ((long)blockIdx.x * 256 + threadIdx.x) * 4;
    if (i + 3 < n) {
        *(float4*)(p + i) = make_float4(0.f, 0.f, 0.f, 0.f);
    } else {
        for (long k = i; k < n; ++k) p[k] = 0.f;
    }
}

// One thread per edge. msg accumulator is float4 S[24] with only
// compile-time component indexing so it MUST live in VGPRs (the round-1
// version spilled: VGPR_Count=64, 2.6 GB scratch writeback, VALUBusy 7.5%).
// Weight loads are wave-uniform -> s_load_dwordx4 broadcasts.
__global__ __launch_bounds__(256, 1)
void edge_kernel(const float* __restrict__ x, const float* __restrict__ ea,
                 const int* __restrict__ ei,
                 const float* __restrict__ Wp, const float* __restrict__ bp,
                 const float* __restrict__ Wa, const float* __restrict__ ba,
                 const float* __restrict__ Wv, const float* __restrict__ bv,
                 float* __restrict__ aggW, float* __restrict__ denomW,
                 float* __restrict__ cntW, int E)
{
    int e = blockIdx.x * 256 + threadIdx.x;
    if (e >= E) return;
    int src = ei[e];
    int dst = ei[E + e];

    float4 S[24];
#pragma unroll
    for (int j = 0; j < 24; ++j) S[j] = ((const float4*)bp)[j];

    const float* xrow = x + (long)src * 64;
    const float* erow = ea + (long)e * 32;

    // ---- msg = [x[src] | ea] @ W_pre + b_pre ----
#pragma unroll 1
    for (int kc = 0; kc < 6; ++kc) {            // 6 chunks of 16 input feats
        const float* sp = (kc < 4) ? (xrow + kc * 16) : (erow + (kc - 4) * 16);
        const float* Wb = Wp + kc * 16 * 96;    // 16 rows of W_pre
#pragma unroll 1
        for (int i = 0; i < 4; ++i) {           // 4 input feats per step
            float4 cc = ((const float4*)sp)[i];
            const float* W0 = Wb + (4 * i + 0) * 96;
            const float* W1 = Wb + (4 * i + 1) * 96;
            const float* W2 = Wb + (4 * i + 2) * 96;
            const float* W3 = Wb + (4 * i + 3) * 96;
#pragma unroll
            for (int j = 0; j < 24; ++j) {      // 96 output cols
                float4 w0 = ((const float4*)W0)[j];
                float4 w1 = ((const float4*)W1)[j];
                float4 w2 = ((const float4*)W2)[j];
                float4 w3 = ((const float4*)W3)[j];
                S[j].x += cc.x * w0.x + cc.y * w1.x + cc.z * w2.x + cc.w * w3.x;
                S[j].y += cc.x * w0.y + cc.y * w1.y + cc.z * w2.y + cc.w * w3.y;
                S[j].z += cc.x * w0.z + cc.y * w1.z + cc.z * w2.z + cc.w * w3.z;
                S[j].w += cc.x * w0.w + cc.y * w1.w + cc.z * w2.w + cc.w * w3.w;
            }
        }
    }
#pragma unroll
    for (int j = 0; j < 24; ++j) {
        S[j].x = lrelu(S[j].x); S[j].y = lrelu(S[j].y);
        S[j].z = lrelu(S[j].z); S[j].w = lrelu(S[j].w);
    }

    // ---- p = exp(msg @ W_att + b_att)  (no max-shift) ----
    float l0 = ba[0], l1 = ba[1], l2 = ba[2], l3 = ba[3];
#pragma unroll
    for (int j = 0; j < 24; ++j) {
        float4 m = S[j];
        float4 w0 = ((const float4*)(Wa + (4 * j + 0) * 4))[0];
        float4 w1 = ((const float4*)(Wa + (4 * j + 1) * 4))[0];
        float4 w2 = ((const float4*)(Wa + (4 * j + 2) * 4))[0];
        float4 w3 = ((const float4*)(Wa + (4 * j + 3) * 4))[0];
        l0 += m.x * w0.x + m.y * w1.x + m.z * w2.x + m.w * w3.x;
        l1 += m.x * w0.y + m.y * w1.y + m.z * w2.y + m.w * w3.y;
        l2 += m.x * w0.z + m.y * w1.z + m.z * w2.z + m.w * w3.z;
        l3 += m.x * w0.w + m.y * w1.w + m.z * w2.w + m.w * w3.w;
    }
    float p0 = __expf(l0), p1 = __expf(l1), p2 = __expf(l2), p3 = __expf(l3);

    // ---- vals = msg @ W_val + b_val, scaled by p_h, scattered to dst ----
    float* aggp = aggW + (long)dst * 96;
#pragma unroll 1
    for (int j4 = 0; j4 < 24; ++j4) {           // 24 col-groups of 4
        float4 acc = ((const float4*)bv)[j4];
        const float* Wc = Wv + 4 * j4;
#pragma unroll
        for (int j = 0; j < 24; ++j) {          // 96 k-rows
            float4 m = S[j];
            float4 w0 = ((const float4*)(Wc + (4 * j + 0) * 96))[0];
            float4 w1 = ((const float4*)(Wc + (4 * j + 1) * 96))[0];
            float4 w2 = ((const float4*)(Wc + (4 * j + 2) * 96))[0];
            float4 w3 = ((const float4*)(Wc + (4 * j + 3) * 96))[0];
            acc.x += m.x * w0.x + m.y * w1.x + m.z * w2.x + m.w * w3.x;
            acc.y += m.x * w0.y + m.y * w1.y + m.z * w2.y + m.w * w3.y;
            acc.z += m.x * w0.z + m.y * w1.z + m.z * w2.z + m.w * w3.z;
            acc.w += m.x * w0.w + m.y * w1.w + m.z * w2.w + m.w * w3.w;
        }
        float ph = (j4 < 6) ? p0 : (j4 < 12) ? p1 : (j4 < 18) ? p2 : p3;
        unsafeAtomicAdd(aggp + 4 * j4 + 0, ph * acc.x);
        unsafeAtomicAdd(aggp + 4 * j4 + 1, ph * acc.y);
        unsafeAtomicAdd(aggp + 4 * j4 + 2, ph * acc.z);
        unsafeAtomicAdd(aggp + 4 * j4 + 3, ph * acc.w);
    }
    float* dn = denomW + (long)dst * 4;
    unsafeAtomicAdd(dn + 0, p0);
    unsafeAtomicAdd(dn + 1, p1);
    unsafeAtomicAdd(dn + 2, p2);
    unsafeAtomicAdd(dn + 3, p3);
    unsafeAtomicAdd(cntW + dst, 1.0f);
}

// out = leaky_relu([x | agg/denom | count] @ W_out + b_out)
__global__ __launch_bounds__(256, 4)
void node_kernel(const float* __restrict__ x, const float* __restrict__ aggW,
                 const float* __restrict__ denomW, const float* __restrict__ cntW,
                 const float* __restrict__ Wo, const float* __restrict__ bo,
                 float* __restrict__ out, int N)
{
    __shared__ float s_in[161][64];
    int n0 = blockIdx.x * 64;
    int j0 = blockIdx.y * 64;

    for (int p = threadIdx.x; p < 161 * 64; p += 256) {
        int k = p >> 6, nl = p & 63;
        int n = n0 + nl;
        float v = 0.f;
        if (n < N) {
            if (k < 64) {
                v = x[(long)n * 64 + k];
            } else if (k < 160) {
                int kk = k - 64;
                float d = denomW[n * 4 + (kk / 24)];
                v = d > 0.f ? aggW[(long)n * 96 + kk] / d : 0.f;
            } else {
                v = cntW[n];
            }
        }
        s_in[k][nl] = v;
    }
    __syncthreads();

    int tj = threadIdx.x & 15;
    int tn = threadIdx.x >> 4;
    float acc[4][4];
#pragma unroll
    for (int i = 0; i < 4; ++i)
#pragma unroll
        for (int c = 0; c < 4; ++c) acc[i][c] = 0.f;

    const float* Wcol = Wo + j0 + tj * 4;
    for (int k = 0; k < 161; ++k) {
        float4 w  = *(const float4*)(Wcol + (long)k * 128);
        float4 iv = *(const float4*)&s_in[k][tn * 4];
        acc[0][0] += iv.x * w.x; acc[0][1] += iv.x * w.y; acc[0][2] += iv.x * w.z; acc[0][3] += iv.x * w.w;
        acc[1][0] += iv.y * w.x; acc[1][1] += iv.y * w.y; acc[1][2] += iv.y * w.z; acc[1][3] += iv.y * w.w;
        acc[2][0] += iv.z * w.x; acc[2][1] += iv.z * w.y; acc[2][2] += iv.z * w.z; acc[2][3] += iv.z * w.w;
        acc[3][0] += iv.w * w.x; acc[3][1] += iv.w * w.y; acc[3][2] += iv.w * w.z; acc[3][3] += iv.w * w.w;
    }
    float4 b = *(const float4*)(bo + j0 + tj * 4);
#pragma unroll
    for (int i = 0; i < 4; ++i) {
        int n = n0 + tn * 4 + i;
        if (n < N) {
            float4 o;
            o.x = lrelu(acc[i][0] + b.x);
            o.y = lrelu(acc[i][1] + b.y);
            o.z = lrelu(acc[i][2] + b.z);
            o.w = lrelu(acc[i][3] + b.w);
            *(float4*)(out + (long)n * 128 + j0 + tj * 4) = o;
        }
    }
}

extern "C" void kernel_launch(void* const* d_in, const int* in_sizes, int n_in,
                              void* d_out, int out_size, void* d_ws, size_t ws_size,
                              hipStream_t stream)
{
    const float* x  = (const float*)d_in[0];
    const float* ea = (const float*)d_in[1];
    const int*   ei = (const int*)d_in[2];
    const float* Wp = (const float*)d_in[3];
    const float* bp = (const float*)d_in[4];
    const float* Wa = (const float*)d_in[5];
    const float* ba = (const float*)d_in[6];
    const float* Wv = (const float*)d_in[7];
    const float* bv = (const float*)d_in[8];
    const float* Wo = (const float*)d_in[9];
    const float* bo = (const float*)d_in[10];
    float* out = (float*)d_out;

    int N = in_sizes[0] / 64;
    int E = in_sizes[2] / 2;

    float* aggW   = (float*)d_ws;
    float* denomW = aggW + (long)N * 96;
    float* cntW   = denomW + (long)N * 4;

    long zn = (long)N * 101;
    long zt = (zn + 3) / 4;
    int  zb = (int)((zt + 255) / 256);
    zero_kernel<<<zb, 256, 0, stream>>>(aggW, zn);

    edge_kernel<<<(E + 255) / 256, 256, 0, stream>>>(
        x, ea, ei, Wp, bp, Wa, ba, Wv, bv, aggW, denomW, cntW, E);

    dim3 ng((N + 63) / 64, 2);
    node_kernel<<<ng, 256, 0, stream>>>(x, aggW, denomW, cntW, Wo, bo, out, N);
}

// Round 4
// 1333.553 us; speedup vs baseline: 3.4182x; 3.4182x over previous
//
#include <hip/hip_runtime.h>

// MultiHeadAttentionConvIndex — CSR gather version, round 4.
// R3 bug: __shfl for the denominator was executed under `if (lane < 48)`,
// leaving source lanes 48..51 exec-masked-off -> ds_bpermute returned
// garbage/0 -> div-by-zero NaN. Fix: shfl executed by all 64 lanes.
//
// ws layout (main path):
//   vals : uint[E*52]   per-edge row = 48 uints (96 bf16 of p*vals) + 4 f32 p
//   agg  : float[N*96]  normalized aggregation (written by gather)
//   cntF : float[N]     in-degree as float
//   cnt_i: int[N]       histogram
//   offs : int[N]       CSR row starts (exclusive prefix)
//   curs : int[N]       scatter cursors
// Fallback (ws too small): round-2 atomic path.

#define NEG 0.01f

__device__ __forceinline__ float lrelu(float v) { return v > 0.f ? v : NEG * v; }

__device__ __forceinline__ unsigned bfpack2(float a, float b) {
    unsigned ua = __float_as_uint(a); ua = (ua + 0x7fff + ((ua >> 16) & 1)) >> 16;
    unsigned ub = __float_as_uint(b); ub = (ub + 0x7fff + ((ub >> 16) & 1)) >> 16;
    return ua | (ub << 16);
}

__global__ void zero_kernel(float* __restrict__ p, long n) {
    long i = ((long)blockIdx.x * 256 + threadIdx.x) * 4;
    if (i + 3 < n) {
        *(float4*)(p + i) = make_float4(0.f, 0.f, 0.f, 0.f);
    } else {
        for (long k = i; k < n; ++k) p[k] = 0.f;
    }
}

__global__ void hist_kernel(const int* __restrict__ ei, int* __restrict__ cnt, int E) {
    int e = blockIdx.x * 256 + threadIdx.x;
    if (e < E) atomicAdd(&cnt[ei[E + e]], 1);
}

// Single-block exclusive scan over cnt[N] -> offs & cursors.
__global__ __launch_bounds__(1024)
void scan_kernel(const int* __restrict__ cnt, int* __restrict__ offs,
                 int* __restrict__ curs, int N) {
    __shared__ int ls[1024];
    int tid = threadIdx.x;
    int chunk = (N + 1023) >> 10;
    int lo = tid * chunk;
    int hi = lo + chunk; if (hi > N) hi = N; if (lo > N) lo = N;
    int s = 0;
    for (int i = lo; i < hi; ++i) s += cnt[i];
    ls[tid] = s;
    __syncthreads();
    for (int off = 1; off < 1024; off <<= 1) {
        int v = 0;
        if (tid >= off) v = ls[tid - off];
        __syncthreads();
        ls[tid] += v;
        __syncthreads();
    }
    int run = ls[tid] - s;              // exclusive prefix of this chunk
    for (int i = lo; i < hi; ++i) {
        offs[i] = run; curs[i] = run; run += cnt[i];
    }
}

// One thread per edge: msg = lrelu([x[src]|ea] @ Wp + bp); p = exp(msg@Wa+ba);
// row[pos] = { bf16(p_h * (msg@Wv+bv)) x96, p x4 }  at CSR slot pos.
__global__ __launch_bounds__(256, 1)
void edge_csr_kernel(const float* __restrict__ x, const float* __restrict__ ea,
                     const int* __restrict__ ei,
                     const float* __restrict__ Wp, const float* __restrict__ bp,
                     const float* __restrict__ Wa, const float* __restrict__ ba,
                     const float* __restrict__ Wv, const float* __restrict__ bv,
                     unsigned* __restrict__ vals, int* __restrict__ curs, int E)
{
    int e = blockIdx.x * 256 + threadIdx.x;
    if (e >= E) return;
    int src = ei[e];
    int dst = ei[E + e];

    float4 S[24];
#pragma unroll
    for (int j = 0; j < 24; ++j) S[j] = ((const float4*)bp)[j];

    const float* xrow = x + (long)src * 64;
    const float* erow = ea + (long)e * 32;

#pragma unroll 1
    for (int kc = 0; kc < 6; ++kc) {
        const float* sp = (kc < 4) ? (xrow + kc * 16) : (erow + (kc - 4) * 16);
        const float* Wb = Wp + kc * 16 * 96;
#pragma unroll 1
        for (int i = 0; i < 4; ++i) {
            float4 cc = ((const float4*)sp)[i];
            const float* W0 = Wb + (4 * i + 0) * 96;
            const float* W1 = Wb + (4 * i + 1) * 96;
            const float* W2 = Wb + (4 * i + 2) * 96;
            const float* W3 = Wb + (4 * i + 3) * 96;
#pragma unroll
            for (int j = 0; j < 24; ++j) {
                float4 w0 = ((const float4*)W0)[j];
                float4 w1 = ((const float4*)W1)[j];
                float4 w2 = ((const float4*)W2)[j];
                float4 w3 = ((const float4*)W3)[j];
                S[j].x += cc.x * w0.x + cc.y * w1.x + cc.z * w2.x + cc.w * w3.x;
                S[j].y += cc.x * w0.y + cc.y * w1.y + cc.z * w2.y + cc.w * w3.y;
                S[j].z += cc.x * w0.z + cc.y * w1.z + cc.z * w2.z + cc.w * w3.z;
                S[j].w += cc.x * w0.w + cc.y * w1.w + cc.z * w2.w + cc.w * w3.w;
            }
        }
    }
#pragma unroll
    for (int j = 0; j < 24; ++j) {
        S[j].x = lrelu(S[j].x); S[j].y = lrelu(S[j].y);
        S[j].z = lrelu(S[j].z); S[j].w = lrelu(S[j].w);
    }

    float l0 = ba[0], l1 = ba[1], l2 = ba[2], l3 = ba[3];
#pragma unroll
    for (int j = 0; j < 24; ++j) {
        float4 m = S[j];
        float4 w0 = ((const float4*)(Wa + (4 * j + 0) * 4))[0];
        float4 w1 = ((const float4*)(Wa + (4 * j + 1) * 4))[0];
        float4 w2 = ((const float4*)(Wa + (4 * j + 2) * 4))[0];
        float4 w3 = ((const float4*)(Wa + (4 * j + 3) * 4))[0];
        l0 += m.x * w0.x + m.y * w1.x + m.z * w2.x + m.w * w3.x;
        l1 += m.x * w0.y + m.y * w1.y + m.z * w2.y + m.w * w3.y;
        l2 += m.x * w0.z + m.y * w1.z + m.z * w2.z + m.w * w3.z;
        l3 += m.x * w0.w + m.y * w1.w + m.z * w2.w + m.w * w3.w;
    }
    float p0 = __expf(l0), p1 = __expf(l1), p2 = __expf(l2), p3 = __expf(l3);

    int pos = atomicAdd(&curs[dst], 1);
    unsigned* row = vals + (long)pos * 52;

#pragma unroll 1
    for (int j4 = 0; j4 < 24; ++j4) {
        float4 acc = ((const float4*)bv)[j4];
        const float* Wc = Wv + 4 * j4;
#pragma unroll
        for (int j = 0; j < 24; ++j) {
            float4 m = S[j];
            float4 w0 = ((const float4*)(Wc + (4 * j + 0) * 96))[0];
            float4 w1 = ((const float4*)(Wc + (4 * j + 1) * 96))[0];
            float4 w2 = ((const float4*)(Wc + (4 * j + 2) * 96))[0];
            float4 w3 = ((const float4*)(Wc + (4 * j + 3) * 96))[0];
            acc.x += m.x * w0.x + m.y * w1.x + m.z * w2.x + m.w * w3.x;
            acc.y += m.x * w0.y + m.y * w1.y + m.z * w2.y + m.w * w3.y;
            acc.z += m.x * w0.z + m.y * w1.z + m.z * w2.z + m.w * w3.z;
            acc.w += m.x * w0.w + m.y * w1.w + m.z * w2.w + m.w * w3.w;
        }
        float ph = (j4 < 6) ? p0 : (j4 < 12) ? p1 : (j4 < 18) ? p2 : p3;
        ((uint2*)row)[j4] = make_uint2(bfpack2(ph * acc.x, ph * acc.y),
                                       bfpack2(ph * acc.z, ph * acc.w));
    }
    *(float4*)(row + 48) = make_float4(p0, p1, p2, p3);
}

// One wave per node: sum its contiguous CSR rows, normalize, write agg+count.
// NOTE: the denominator shfl MUST be executed by all 64 lanes — source lanes
// 48..51 have to be active or ds_bpermute pulls garbage (R3 NaN bug).
__global__ __launch_bounds__(256, 4)
void gather_kernel(const unsigned* __restrict__ vals, const int* __restrict__ offs,
                   const int* __restrict__ cnt, float* __restrict__ agg,
                   float* __restrict__ cntF, int N)
{
    int node = blockIdx.x * 4 + (threadIdx.x >> 6);
    int lane = threadIdx.x & 63;
    if (node >= N) return;           // wave-uniform: whole wave exits together
    int start = offs[node];
    int deg = cnt[node];

    float s0 = 0.f, s1 = 0.f, sp = 0.f;
    if (lane < 52) {
        const unsigned* p = vals + (long)start * 52 + lane;
        for (int r = 0; r < deg; ++r, p += 52) {
            unsigned v = *p;
            if (lane < 48) {
                s0 += __uint_as_float(v << 16);
                s1 += __uint_as_float(v & 0xffff0000u);
            } else {
                sp += __uint_as_float(v);
            }
        }
    }
    // All 64 lanes execute the shfl (sources 48..51 must be active).
    int srcl = 48 + ((lane < 48) ? (lane / 12) : 0);
    float d = __shfl(sp, srcl, 64);

    if (lane < 48) {
        float2 o;
        if (deg > 0) { o.x = s0 / d; o.y = s1 / d; }
        else         { o.x = 0.f;    o.y = 0.f; }
        *(float2*)(agg + (long)node * 96 + 2 * lane) = o;
    } else if (lane == 48) {
        cntF[node] = (float)deg;
    }
}

// out = leaky_relu([x | agg | count] @ W_out + b_out)
__global__ __launch_bounds__(256, 4)
void node_kernel(const float* __restrict__ x, const float* __restrict__ aggW,
                 const float* __restrict__ cntF,
                 const float* __restrict__ Wo, const float* __restrict__ bo,
                 float* __restrict__ out, int N)
{
    __shared__ float s_in[161][64];
    int n0 = blockIdx.x * 64;
    int j0 = blockIdx.y * 64;

    for (int p = threadIdx.x; p < 161 * 64; p += 256) {
        int k = p >> 6, nl = p & 63;
        int n = n0 + nl;
        float v = 0.f;
        if (n < N) {
            if (k < 64)       v = x[(long)n * 64 + k];
            else if (k < 160) v = aggW[(long)n * 96 + (k - 64)];
            else              v = cntF[n];
        }
        s_in[k][nl] = v;
    }
    __syncthreads();

    int tj = threadIdx.x & 15;
    int tn = threadIdx.x >> 4;
    float acc[4][4];
#pragma unroll
    for (int i = 0; i < 4; ++i)
#pragma unroll
        for (int c = 0; c < 4; ++c) acc[i][c] = 0.f;

    const float* Wcol = Wo + j0 + tj * 4;
    for (int k = 0; k < 161; ++k) {
        float4 w  = *(const float4*)(Wcol + (long)k * 128);
        float4 iv = *(const float4*)&s_in[k][tn * 4];
        acc[0][0] += iv.x * w.x; acc[0][1] += iv.x * w.y; acc[0][2] += iv.x * w.z; acc[0][3] += iv.x * w.w;
        acc[1][0] += iv.y * w.x; acc[1][1] += iv.y * w.y; acc[1][2] += iv.y * w.z; acc[1][3] += iv.y * w.w;
        acc[2][0] += iv.z * w.x; acc[2][1] += iv.z * w.y; acc[2][2] += iv.z * w.z; acc[2][3] += iv.z * w.w;
        acc[3][0] += iv.w * w.x; acc[3][1] += iv.w * w.y; acc[3][2] += iv.w * w.z; acc[3][3] += iv.w * w.w;
    }
    float4 b = *(const float4*)(bo + j0 + tj * 4);
#pragma unroll
    for (int i = 0; i < 4; ++i) {
        int n = n0 + tn * 4 + i;
        if (n < N) {
            float4 o;
            o.x = lrelu(acc[i][0] + b.x);
            o.y = lrelu(acc[i][1] + b.y);
            o.z = lrelu(acc[i][2] + b.z);
            o.w = lrelu(acc[i][3] + b.w);
            *(float4*)(out + (long)n * 128 + j0 + tj * 4) = o;
        }
    }
}

// ---------------- fallback (round-2 atomic path, used if ws too small) -----
__global__ __launch_bounds__(256, 1)
void edge_atm_kernel(const float* __restrict__ x, const float* __restrict__ ea,
                     const int* __restrict__ ei,
                     const float* __restrict__ Wp, const float* __restrict__ bp,
                     const float* __restrict__ Wa, const float* __restrict__ ba,
                     const float* __restrict__ Wv, const float* __restrict__ bv,
                     float* __restrict__ aggW, float* __restrict__ denomW,
                     float* __restrict__ cntW, int E)
{
    int e = blockIdx.x * 256 + threadIdx.x;
    if (e >= E) return;
    int src = ei[e];
    int dst = ei[E + e];
    float4 S[24];
#pragma unroll
    for (int j = 0; j < 24; ++j) S[j] = ((const float4*)bp)[j];
    const float* xrow = x + (long)src * 64;
    const float* erow = ea + (long)e * 32;
#pragma unroll 1
    for (int kc = 0; kc < 6; ++kc) {
        const float* sp = (kc < 4) ? (xrow + kc * 16) : (erow + (kc - 4) * 16);
        const float* Wb = Wp + kc * 16 * 96;
#pragma unroll 1
        for (int i = 0; i < 4; ++i) {
            float4 cc = ((const float4*)sp)[i];
#pragma unroll
            for (int j = 0; j < 24; ++j) {
                float4 w0 = ((const float4*)(Wb + (4 * i + 0) * 96))[j];
                float4 w1 = ((const float4*)(Wb + (4 * i + 1) * 96))[j];
                float4 w2 = ((const float4*)(Wb + (4 * i + 2) * 96))[j];
                float4 w3 = ((const float4*)(Wb + (4 * i + 3) * 96))[j];
                S[j].x += cc.x * w0.x + cc.y * w1.x + cc.z * w2.x + cc.w * w3.x;
                S[j].y += cc.x * w0.y + cc.y * w1.y + cc.z * w2.y + cc.w * w3.y;
                S[j].z += cc.x * w0.z + cc.y * w1.z + cc.z * w2.z + cc.w * w3.z;
                S[j].w += cc.x * w0.w + cc.y * w1.w + cc.z * w2.w + cc.w * w3.w;
            }
        }
    }
#pragma unroll
    for (int j = 0; j < 24; ++j) {
        S[j].x = lrelu(S[j].x); S[j].y = lrelu(S[j].y);
        S[j].z = lrelu(S[j].z); S[j].w = lrelu(S[j].w);
    }
    float l0 = ba[0], l1 = ba[1], l2 = ba[2], l3 = ba[3];
#pragma unroll
    for (int j = 0; j < 24; ++j) {
        float4 m = S[j];
        float4 w0 = ((const float4*)(Wa + (4 * j + 0) * 4))[0];
        float4 w1 = ((const float4*)(Wa + (4 * j + 1) * 4))[0];
        float4 w2 = ((const float4*)(Wa + (4 * j + 2) * 4))[0];
        float4 w3 = ((const float4*)(Wa + (4 * j + 3) * 4))[0];
        l0 += m.x * w0.x + m.y * w1.x + m.z * w2.x + m.w * w3.x;
        l1 += m.x * w0.y + m.y * w1.y + m.z * w2.y + m.w * w3.y;
        l2 += m.x * w0.z + m.y * w1.z + m.z * w2.z + m.w * w3.z;
        l3 += m.x * w0.w + m.y * w1.w + m.z * w2.w + m.w * w3.w;
    }
    float p0 = __expf(l0), p1 = __expf(l1), p2 = __expf(l2), p3 = __expf(l3);
    float* aggp = aggW + (long)dst * 96;
#pragma unroll 1
    for (int j4 = 0; j4 < 24; ++j4) {
        float4 acc = ((const float4*)bv)[j4];
        const float* Wc = Wv + 4 * j4;
#pragma unroll
        for (int j = 0; j < 24; ++j) {
            float4 m = S[j];
            float4 w0 = ((const float4*)(Wc + (4 * j + 0) * 96))[0];
            float4 w1 = ((const float4*)(Wc + (4 * j + 1) * 96))[0];
            float4 w2 = ((const float4*)(Wc + (4 * j + 2) * 96))[0];
            float4 w3 = ((const float4*)(Wc + (4 * j + 3) * 96))[0];
            acc.x += m.x * w0.x + m.y * w1.x + m.z * w2.x + m.w * w3.x;
            acc.y += m.x * w0.y + m.y * w1.y + m.z * w2.y + m.w * w3.y;
            acc.z += m.x * w0.z + m.y * w1.z + m.z * w2.z + m.w * w3.z;
            acc.w += m.x * w0.w + m.y * w1.w + m.z * w2.w + m.w * w3.w;
        }
        float ph = (j4 < 6) ? p0 : (j4 < 12) ? p1 : (j4 < 18) ? p2 : p3;
        unsafeAtomicAdd(aggp + 4 * j4 + 0, ph * acc.x);
        unsafeAtomicAdd(aggp + 4 * j4 + 1, ph * acc.y);
        unsafeAtomicAdd(aggp + 4 * j4 + 2, ph * acc.z);
        unsafeAtomicAdd(aggp + 4 * j4 + 3, ph * acc.w);
    }
    float* dn = denomW + (long)dst * 4;
    unsafeAtomicAdd(dn + 0, p0);
    unsafeAtomicAdd(dn + 1, p1);
    unsafeAtomicAdd(dn + 2, p2);
    unsafeAtomicAdd(dn + 3, p3);
    unsafeAtomicAdd(cntW + dst, 1.0f);
}

__global__ __launch_bounds__(256, 4)
void node_atm_kernel(const float* __restrict__ x, const float* __restrict__ aggW,
                     const float* __restrict__ denomW, const float* __restrict__ cntW,
                     const float* __restrict__ Wo, const float* __restrict__ bo,
                     float* __restrict__ out, int N)
{
    __shared__ float s_in[161][64];
    int n0 = blockIdx.x * 64;
    int j0 = blockIdx.y * 64;
    for (int p = threadIdx.x; p < 161 * 64; p += 256) {
        int k = p >> 6, nl = p & 63;
        int n = n0 + nl;
        float v = 0.f;
        if (n < N) {
            if (k < 64) v = x[(long)n * 64 + k];
            else if (k < 160) {
                int kk = k - 64;
                float d = denomW[n * 4 + (kk / 24)];
                v = d > 0.f ? aggW[(long)n * 96 + kk] / d : 0.f;
            } else v = cntW[n];
        }
        s_in[k][nl] = v;
    }
    __syncthreads();
    int tj = threadIdx.x & 15;
    int tn = threadIdx.x >> 4;
    float acc[4][4];
#pragma unroll
    for (int i = 0; i < 4; ++i)
#pragma unroll
        for (int c = 0; c < 4; ++c) acc[i][c] = 0.f;
    const float* Wcol = Wo + j0 + tj * 4;
    for (int k = 0; k < 161; ++k) {
        float4 w  = *(const float4*)(Wcol + (long)k * 128);
        float4 iv = *(const float4*)&s_in[k][tn * 4];
        acc[0][0] += iv.x * w.x; acc[0][1] += iv.x * w.y; acc[0][2] += iv.x * w.z; acc[0][3] += iv.x * w.w;
        acc[1][0] += iv.y * w.x; acc[1][1] += iv.y * w.y; acc[1][2] += iv.y * w.z; acc[1][3] += iv.y * w.w;
        acc[2][0] += iv.z * w.x; acc[2][1] += iv.z * w.y; acc[2][2] += iv.z * w.z; acc[2][3] += iv.z * w.w;
        acc[3][0] += iv.w * w.x; acc[3][1] += iv.w * w.y; acc[3][2] += iv.w * w.z; acc[3][3] += iv.w * w.w;
    }
    float4 b = *(const float4*)(bo + j0 + tj * 4);
#pragma unroll
    for (int i = 0; i < 4; ++i) {
        int n = n0 + tn * 4 + i;
        if (n < N) {
            float4 o;
            o.x = lrelu(acc[i][0] + b.x);
            o.y = lrelu(acc[i][1] + b.y);
            o.z = lrelu(acc[i][2] + b.z);
            o.w = lrelu(acc[i][3] + b.w);
            *(float4*)(out + (long)n * 128 + j0 + tj * 4) = o;
        }
    }
}

extern "C" void kernel_launch(void* const* d_in, const int* in_sizes, int n_in,
                              void* d_out, int out_size, void* d_ws, size_t ws_size,
                              hipStream_t stream)
{
    const float* x  = (const float*)d_in[0];
    const float* ea = (const float*)d_in[1];
    const int*   ei = (const int*)d_in[2];
    const float* Wp = (const float*)d_in[3];
    const float* bp = (const float*)d_in[4];
    const float* Wa = (const float*)d_in[5];
    const float* ba = (const float*)d_in[6];
    const float* Wv = (const float*)d_in[7];
    const float* bv = (const float*)d_in[8];
    const float* Wo = (const float*)d_in[9];
    const float* bo = (const float*)d_in[10];
    float* out = (float*)d_out;

    int N = in_sizes[0] / 64;
    int E = in_sizes[2] / 2;

    size_t need = (size_t)E * 52 * 4 + (size_t)N * 96 * 4 + (size_t)N * 4 * 4;

    if (ws_size >= need) {
        unsigned* vals = (unsigned*)d_ws;
        float* aggW = (float*)(vals + (long)E * 52);
        float* cntF = aggW + (long)N * 96;
        int*   cnti = (int*)(cntF + N);
        int*   offs = cnti + N;
        int*   curs = offs + N;

        zero_kernel<<<(N / 4 + 255) / 256 + 1, 256, 0, stream>>>((float*)cnti, N);
        hist_kernel<<<(E + 255) / 256, 256, 0, stream>>>(ei, cnti, E);
        scan_kernel<<<1, 1024, 0, stream>>>(cnti, offs, curs, N);
        edge_csr_kernel<<<(E + 255) / 256, 256, 0, stream>>>(
            x, ea, ei, Wp, bp, Wa, ba, Wv, bv, vals, curs, E);
        gather_kernel<<<(N + 3) / 4, 256, 0, stream>>>(vals, offs, cnti, aggW, cntF, N);
        dim3 ng((N + 63) / 64, 2);
        node_kernel<<<ng, 256, 0, stream>>>(x, aggW, cntF, Wo, bo, out, N);
    } else {
        float* aggW   = (float*)d_ws;
        float* denomW = aggW + (long)N * 96;
        float* cntW   = denomW + (long)N * 4;
        long zn = (long)N * 101;
        int  zb = (int)(((zn + 3) / 4 + 255) / 256);
        zero_kernel<<<zb, 256, 0, stream>>>(aggW, zn);
        edge_atm_kernel<<<(E + 255) / 256, 256, 0, stream>>>(
            x, ea, ei, Wp, bp, Wa, ba, Wv, bv, aggW, denomW, cntW, E);
        dim3 ng((N + 63) / 64, 2);
        node_atm_kernel<<<ng, 256, 0, stream>>>(x, aggW, denomW, cntW, Wo, bo, out, N);
    }
}